// Round 11
// baseline (50.020 us; speedup 1.0000x reference)
//
#include <hip/hip_runtime.h>
#include <hip/hip_bf16.h>

// MyDeConv1D as GEMM: out[b,t,f] = sum_{j,c} x[b,t+28-4j,c]*W[c,j,f] + cnt(t)*256*bias[f]
// M=32768, N=256, K=2048, bf16 MFMA 16x16x32.
// R11: 1-wave blocks, BARRIER-FREE. 2048 blocks of 64 thr (8 waves/CU), each
//     wave owns 64r x 64f with private 11.7KB LDS (2-buf, 92x32ch chunks).
//     No __syncthreads anywhere; 8 desynchronized waves/CU hide each other's
//     vmcnt/lgkmcnt stalls. Swizzle slot = g ^ ((row>>1)&3) (bank-walked:
//     exact minimum for b128 read AND write). B ring depth-4, A ring depth-2.

#define B_    16
#define T_    2048
#define C_    256
#define KT    8
#define F_    256
#define SH    28
#define BT    64
#define ROWS  (BT + SH)        // 92
#define CH    32               // channels per chunk
#define CHW   (ROWS * CH)      // 2944 ushorts per buffer (5888 B)
#define NTASK (ROWS * 4)       // 368 16B-granule staging tasks per chunk

typedef __attribute__((ext_vector_type(8))) short short8;
typedef __attribute__((ext_vector_type(4))) float floatx4;

// Wf frag order: fid = S*16 + g, S = cs*8 + j (cs: 32-ch chunk, j: tap).
// frag (S,g): lane(l16,q) holds B[k=q*8+i][f=g*16+l16], c = cs*32 + q*8 + i.
__global__ __launch_bounds__(256) void wprep_kernel(const float* __restrict__ W,
                                                    ushort* __restrict__ Wf) {
    const int tid  = threadIdx.x;
    const int fid  = blockIdx.x * 4 + (tid >> 6);   // 0..1023
    const int lane = tid & 63;
    const int g    = fid & 15;
    const int S    = fid >> 4;
    const int j    = S & 7, cs = S >> 3;
    const int c0   = cs * 32 + (lane >> 4) * 8;
    const int f    = g * 16 + (lane & 15);
    short8 pk;
    #pragma unroll
    for (int i = 0; i < 8; ++i) {
        __hip_bfloat16 h = __float2bfloat16(W[((c0 + i) * KT + j) * F_ + f]);
        pk[i] = *reinterpret_cast<const short*>(&h);
    }
    *reinterpret_cast<short8*>(Wf + (size_t)fid * 512 + lane * 8) = pk;
}

__device__ inline short8 cvt8(float4 a, float4 b) {
    float v[8] = {a.x, a.y, a.z, a.w, b.x, b.y, b.z, b.w};
    short8 r;
    #pragma unroll
    for (int i = 0; i < 8; ++i) {
        __hip_bfloat16 h = __float2bfloat16(v[i]);
        r[i] = *reinterpret_cast<const short*>(&h);
    }
    return r;
}

__global__ __launch_bounds__(64, 2) void deconv_kernel(
        const float* __restrict__ x, const ushort* __restrict__ Wf,
        const float* __restrict__ bias, float* __restrict__ out) {
    __shared__ ushort xs[2 * CHW];                  // 11.5 KiB, wave-private
    const int bid  = blockIdx.x;                    // (tt*16 + b)*4 + ft
    const int ft   = bid & 3;
    const int tb   = bid >> 2;
    const int b    = tb & 15;
    const int t0   = (tb >> 4) * BT;
    const int lane = threadIdx.x;                   // 64 threads = 1 wave
    const int l16  = lane & 15, q = lane >> 4;

    // staging: 368 tasks (row=task>>2, g=task&3 -> 8 channels), 6 rounds of 64.
    float4 SA[6], SB[6];

#define STAGE_LOAD(cs_) do {                                                   \
        _Pragma("unroll")                                                      \
        for (int k = 0; k < 6; ++k) {                                          \
            const int task_ = lane + k * 64;                                   \
            const int row_  = task_ >> 2, g_ = task_ & 3;                      \
            SA[k] = make_float4(0.f, 0.f, 0.f, 0.f);                           \
            SB[k] = make_float4(0.f, 0.f, 0.f, 0.f);                           \
            if (task_ < NTASK && t0 + row_ < T_) {                             \
                const float4* p_ = reinterpret_cast<const float4*>(            \
                    x + ((size_t)(b * T_ + t0 + row_) * C_ +                   \
                         (cs_) * CH + g_ * 8));                                \
                SA[k] = p_[0]; SB[k] = p_[1];                                  \
            } } } while (0)

#define STAGE_WRITE(buf_) do {                                                 \
        ushort* d_ = xs + (buf_) * CHW;                                        \
        _Pragma("unroll")                                                      \
        for (int k = 0; k < 6; ++k) {                                          \
            const int task_ = lane + k * 64;                                   \
            const int row_  = task_ >> 2, g_ = task_ & 3;                      \
            if (task_ < NTASK) {                                               \
                const int sl_ = g_ ^ ((row_ >> 1) & 3);                        \
                *reinterpret_cast<short8*>(                                    \
                    d_ + row_ * CH + sl_ * 8) = cvt8(SA[k], SB[k]);            \
            } } } while (0)

    // A frag (tap j, frag mf): row = SH-4j + mf*16 + l16 (<=91),
    // logical granule q, phys slot = q ^ ((row>>1)&3).
#define LOAD_A(buf_, j_, arr) do {                                             \
        const int rb_ = SH - 4 * (j_) + l16;                                   \
        _Pragma("unroll")                                                      \
        for (int mf = 0; mf < 4; ++mf) {                                       \
            const int row_ = rb_ + mf * 16;                                    \
            const int sl_  = q ^ ((row_ >> 1) & 3);                            \
            arr[mf] = *reinterpret_cast<const short8*>(                        \
                xs + (buf_) * CHW + row_ * CH + sl_ * 8);                      \
        } } while (0)

#define LOAD_B(S_, arr) do {                                                   \
        const ushort* p_ = wbase + (size_t)(S_) * 8192;                        \
        _Pragma("unroll")                                                      \
        for (int nf = 0; nf < 4; ++nf)                                         \
            arr[nf] = *reinterpret_cast<const short8*>(p_ + nf * 512);         \
        } while (0)

#define DO_MFMA(aa, bb) do {                                                   \
        _Pragma("unroll")                                                      \
        for (int mf = 0; mf < 4; ++mf)                                         \
            _Pragma("unroll")                                                  \
            for (int nf = 0; nf < 4; ++nf)                                     \
                acc[mf][nf] = __builtin_amdgcn_mfma_f32_16x16x32_bf16(         \
                    aa[mf], bb[nf], acc[mf][nf], 0, 0, 0);                     \
        } while (0)

    const ushort* wbase = Wf + (size_t)(ft * 4) * 512 + lane * 8;

    float bf4[4];
    #pragma unroll
    for (int nf = 0; nf < 4; ++nf) bf4[nf] = bias[ft * 64 + nf * 16 + l16];

    floatx4 acc[4][4];
    #pragma unroll
    for (int mf = 0; mf < 4; ++mf)
        #pragma unroll
        for (int nf = 0; nf < 4; ++nf)
            acc[mf][nf] = (floatx4){0.f, 0.f, 0.f, 0.f};

    short8 aR[2][4];                 // depth-2 A ring
    short8 bR[4][4];                 // depth-4 B ring (8 taps % 4 == 0: stable)

    // ---- prologue: stage chunk 0, prime B ring ----
    STAGE_LOAD(0);
    LOAD_B(0, bR[0]);
    LOAD_B(1, bR[1]);
    STAGE_WRITE(0);
    LOAD_A(0, 0, aR[0]);             // lgkmcnt orders write->read (same wave)

    for (int cs = 0; cs < 8; ++cs) {
        const int buf = cs & 1;
        const int Sb  = cs * 8;
        if (cs < 7) STAGE_LOAD(cs + 1);          // x loads in flight under MFMA
        #pragma unroll
        for (int j = 0; j < 8; ++j) {
            LOAD_B((Sb + j + 2) & 63, bR[(j + 2) & 3]);   // consumed 2 taps later
            if (j < 7) LOAD_A(buf, j + 1, aR[(j + 1) & 1]);
            __builtin_amdgcn_s_setprio(1);
            DO_MFMA(aR[j & 1], bR[j & 3]);
            __builtin_amdgcn_s_setprio(0);
        }
        if (cs < 7) {
            STAGE_WRITE(buf ^ 1);
            LOAD_A(buf ^ 1, 0, aR[0]);
        }
    }

    // epilogue: + cnt(t)*256*bias; C/D map col=l16 (f), row=q*4+r
    #pragma unroll
    for (int mf = 0; mf < 4; ++mf) {
        #pragma unroll
        for (int nf = 0; nf < 4; ++nf) {
            const int f = ft * 64 + nf * 16 + l16;
            #pragma unroll
            for (int r = 0; r < 4; ++r) {
                const int t = t0 + mf * 16 + q * 4 + r;
                const int jmin = (t < T_ - SH) ? 0 : (((t - (T_ - SH)) >> 2) + 1);
                out[(size_t)(b * T_ + t) * F_ + f] =
                    acc[mf][nf][r] + (float)(8 - jmin) * 256.0f * bf4[nf];
            }
        }
    }
#undef STAGE_LOAD
#undef STAGE_WRITE
#undef LOAD_A
#undef LOAD_B
#undef DO_MFMA
}

extern "C" void kernel_launch(void* const* d_in, const int* in_sizes, int n_in,
                              void* d_out, int out_size, void* d_ws, size_t ws_size,
                              hipStream_t stream) {
    const float* x    = (const float*)d_in[0];
    const float* W    = (const float*)d_in[1];   // (C,KT,F)
    const float* bias = (const float*)d_in[2];
    float* out = (float*)d_out;
    ushort* Wf = (ushort*)d_ws;                  // 1 MiB scratch

    wprep_kernel<<<256, 256, 0, stream>>>(W, Wf);
    deconv_kernel<<<2048, 64, 0, stream>>>(x, Wf, bias, out);
}